// Round 8
// baseline (73.272 us; speedup 1.0000x reference)
//
#include <hip/hip_runtime.h>

#define NB 8
#define TE 256
#define TD 256
#define DE 512
#define QT 4

// K2 = 2*log2(e): exp2(K2*x) = e^{2x}; tanh(x) = 1 - 2/(e^{2x}+1).
#define K2SCALE 2.8853900817779268f

typedef short bf16x8 __attribute__((ext_vector_type(8)));           // 8 bf16 (4 VGPR)
typedef float f32x4 __attribute__((ext_vector_type(4)));            // MFMA acc
typedef unsigned short u16x8 __attribute__((ext_vector_type(8)));   // 16 B staging

// round-to-nearest-even f32 -> bf16
static __device__ __forceinline__ unsigned short f2bf(float x) {
  unsigned int u = __float_as_uint(x);
  u += 0x7fffu + ((u >> 16) & 1u);
  return (unsigned short)(u >> 16);
}

// split f32 -> hi (ROUNDED bf16) + lo (rounded residual).
static __device__ __forceinline__ void split8(
    const float4& x0, const float4& x1, u16x8& h, u16x8& l) {
  float xs[8] = {x0.x, x0.y, x0.z, x0.w, x1.x, x1.y, x1.z, x1.w};
  #pragma unroll
  for (int j = 0; j < 8; ++j) {
    unsigned short hh = f2bf(xs[j]);
    float hf = __uint_as_float((unsigned int)hh << 16);
    h[j] = hh;
    l[j] = f2bf(xs[j] - hf);
  }
}

// ---- convB: W [512x512] f32 -> TRANSPOSED hi/lo bf16 BT[n][k] (32x32 tiles) ----
__global__ __launch_bounds__(256) void convB(
    const float* __restrict__ w0, unsigned short* __restrict__ h0, unsigned short* __restrict__ l0,
    const float* __restrict__ w1, unsigned short* __restrict__ h1, unsigned short* __restrict__ l1)
{
  const float* W = blockIdx.z ? w1 : w0;
  unsigned short* H = blockIdx.z ? h1 : h0;
  unsigned short* L = blockIdx.z ? l1 : l0;
  __shared__ unsigned short sh[32][33], sl[32][33];
  const int t = threadIdx.x;
  const int k0 = blockIdx.y * 32, n0 = blockIdx.x * 32;
  const int r = t >> 3, c = (t & 7) * 4;
  float4 x = *(const float4*)(W + (size_t)(k0 + r) * DE + n0 + c);
  float xs[4] = {x.x, x.y, x.z, x.w};
  #pragma unroll
  for (int j = 0; j < 4; ++j) {
    unsigned short hh = f2bf(xs[j]);
    float hf = __uint_as_float((unsigned int)hh << 16);
    sh[r][c + j] = hh;
    sl[r][c + j] = f2bf(xs[j] - hf);
  }
  __syncthreads();
  ushort4 oh, ol;
  oh.x = sh[c + 0][r]; oh.y = sh[c + 1][r]; oh.z = sh[c + 2][r]; oh.w = sh[c + 3][r];
  ol.x = sl[c + 0][r]; ol.y = sl[c + 1][r]; ol.z = sl[c + 2][r]; ol.w = sl[c + 3][r];
  *(ushort4*)(H + (size_t)(n0 + r) * DE + k0 + c) = oh;
  *(ushort4*)(L + (size_t)(n0 + r) * DE + k0 + c) = ol;
}

// ---- gemm_mfma: C = exp2(K2 * A@B), A f32 split in-register, dbuf LDS ---------
// (byte-identical to R7: XCD-clustered 1D-512 grid)
__global__ __launch_bounds__(256) void gemm_mfma(
    const float* __restrict__ A0,
    const unsigned short* __restrict__ BH0, const unsigned short* __restrict__ BL0,
    float* __restrict__ C0,
    const float* __restrict__ A1,
    const unsigned short* __restrict__ BH1, const unsigned short* __restrict__ BL1,
    float* __restrict__ C1)
{
  const int blk = blockIdx.x;
  const int xcd = blk & 7;
  const int j = blk >> 3;                   // 0..63
  const int panel = xcd * 8 + (j & 7);      // 0..63: (m-block, matrix) pair
  const int bx = j >> 3;                    // 0..7  n-block
  const int by = panel & 31;                // 0..31 m-block
  const int bz = panel >> 5;                // 0..1  matrix select
  const float*          A  = bz ? A1  : A0;
  const unsigned short* BH = bz ? BH1 : BH0;
  const unsigned short* BL = bz ? BL1 : BL0;
  float*                C  = bz ? C1  : C0;
  const int tid  = threadIdx.x;
  const int lane = tid & 63;
  const int wave = tid >> 6;
  const int wm = wave >> 1, wn = wave & 1;
  const int g = lane >> 4, r16 = lane & 15;
  const int m0 = by * 64, n0 = bx * 64;
  __shared__ __align__(16) unsigned short Ah[2][64][40], Al[2][64][40];
  __shared__ __align__(16) unsigned short Bh[2][64][40], Bl[2][64][40];
  const int arow = tid >> 2;            // 0..63
  const int apart = (tid & 3) * 8;      // 8-elem (16 B) piece of a 32-elem row

  float4 a00, a01;
  u16x8 pb, plb;
#define LOADTILE(KT) do {                                                   \
    const size_t ko = (size_t)(KT) * 32 + apart;                            \
    const float* pa_ = A + (size_t)(m0 + arow) * 512 + ko;                  \
    a00 = *(const float4*)pa_;  a01 = *(const float4*)(pa_ + 4);            \
    pb  = *(const u16x8*)(BH + (size_t)(n0 + arow) * 512 + ko);             \
    plb = *(const u16x8*)(BL + (size_t)(n0 + arow) * 512 + ko);             \
  } while (0)
#define STORETILE(BUF) do {                                                 \
    u16x8 h0_, l0_;                                                         \
    split8(a00, a01, h0_, l0_);                                             \
    *(u16x8*)&Ah[BUF][arow][apart] = h0_;                                   \
    *(u16x8*)&Al[BUF][arow][apart] = l0_;                                   \
    *(u16x8*)&Bh[BUF][arow][apart] = pb;                                    \
    *(u16x8*)&Bl[BUF][arow][apart] = plb;                                   \
  } while (0)

  f32x4 accm[2][2], acce[2][2];
  #pragma unroll
  for (int mt = 0; mt < 2; ++mt)
    #pragma unroll
    for (int nt = 0; nt < 2; ++nt) {
      accm[mt][nt] = (f32x4){0.f, 0.f, 0.f, 0.f};
      acce[mt][nt] = (f32x4){0.f, 0.f, 0.f, 0.f};
    }

  LOADTILE(0);
  STORETILE(0);
  __syncthreads();

  for (int kt = 0; kt < 16; ++kt) {
    const int cur = kt & 1;
    if (kt + 1 < 16) LOADTILE(kt + 1);  // issue early; hides under compute
    bf16x8 ah[2], al[2], bh[2], bl[2];
    #pragma unroll
    for (int mt = 0; mt < 2; ++mt) {
      ah[mt] = *(const bf16x8*)&Ah[cur][wm * 32 + mt * 16 + r16][g * 8];
      al[mt] = *(const bf16x8*)&Al[cur][wm * 32 + mt * 16 + r16][g * 8];
    }
    #pragma unroll
    for (int nt = 0; nt < 2; ++nt) {
      bh[nt] = *(const bf16x8*)&Bh[cur][wn * 32 + nt * 16 + r16][g * 8];
      bl[nt] = *(const bf16x8*)&Bl[cur][wn * 32 + nt * 16 + r16][g * 8];
    }
    #pragma unroll
    for (int mt = 0; mt < 2; ++mt)
      #pragma unroll
      for (int nt = 0; nt < 2; ++nt) {
        accm[mt][nt] = __builtin_amdgcn_mfma_f32_16x16x32_bf16(ah[mt], bh[nt], accm[mt][nt], 0, 0, 0);
        acce[mt][nt] = __builtin_amdgcn_mfma_f32_16x16x32_bf16(al[mt], bh[nt], acce[mt][nt], 0, 0, 0);
        acce[mt][nt] = __builtin_amdgcn_mfma_f32_16x16x32_bf16(ah[mt], bl[nt], acce[mt][nt], 0, 0, 0);
      }
    if (kt + 1 < 16) STORETILE(cur ^ 1);  // other buffer: no hazard
    __syncthreads();                       // single barrier per k-tile
  }
#undef LOADTILE
#undef STORETILE

  #pragma unroll
  for (int mt = 0; mt < 2; ++mt)
    #pragma unroll
    for (int nt = 0; nt < 2; ++nt)
      #pragma unroll
      for (int jj = 0; jj < 4; ++jj) {
        float vsum = accm[mt][nt][jj] + acce[mt][nt][jj];
        int row = m0 + wm * 32 + mt * 16 + g * 4 + jj;
        int col = n0 + wn * 32 + nt * 16 + r16;
        C[(size_t)row * 512 + col] = __builtin_amdgcn_exp2f(vsum * K2SCALE);
      }
}

// ---- scores: s[b,q,t] = -2 * sum_f v[f]/(ew[t,f]*eu[q,f]+1)  -------------------
// Split from the old monolithic attn so the score phase runs at FULL occupancy:
// grid = 8b x 64qt x 4tt = 2048 blocks x 256 thr (4 waves), no LDS, no barriers
// -> 8 blocks/CU = 8 waves/SIMD (vs 4 before; attn was stall-bound at 31% occ).
// b = blk&7 keeps the XCD locality of ew[b]. Each wave owns 16 t.
__global__ __launch_bounds__(256) void scores(
    const float* __restrict__ ws, const float* __restrict__ uh,
    const float* __restrict__ va, float* __restrict__ out_s)
{
  const int tid  = threadIdx.x;
  const int wave = tid >> 6;
  const int lane = tid & 63;
  const int blk  = blockIdx.x;
  const int b    = blk & 7;                // XCD-locality: batch <-> XCD
  const int rest = blk >> 3;               // 0..255
  const int q0   = (rest & 63) * QT;
  const int tt   = rest >> 6;              // 0..3
  const int t0   = tt * 64 + wave * 16;
  const int fbase = lane * 8;

  float4 v0 = *(const float4*)(va + fbase);
  float4 v1 = *(const float4*)(va + fbase + 4);
  float v[8] = {v0.x, v0.y, v0.z, v0.w, v1.x, v1.y, v1.z, v1.w};

  float eu[QT][8];
  #pragma unroll
  for (int q = 0; q < QT; ++q) {
    const float* up = uh + (size_t)(b * TD + q0 + q) * DE + fbase;
    float4 u0 = *(const float4*)(up);
    float4 u1 = *(const float4*)(up + 4);
    eu[q][0] = u0.x; eu[q][1] = u0.y; eu[q][2] = u0.z; eu[q][3] = u0.w;
    eu[q][4] = u1.x; eu[q][5] = u1.y; eu[q][6] = u1.z; eu[q][7] = u1.w;
  }

  const float* wp = ws + (size_t)(b * TE + t0) * DE + fbase;
  float4 w0 = *(const float4*)(wp);
  float4 w1 = *(const float4*)(wp + 4);
  for (int t = t0; t < t0 + 16; ++t) {
    float cw[8] = {w0.x, w0.y, w0.z, w0.w, w1.x, w1.y, w1.z, w1.w};
    // prefetch next row; last iter reads one row past (max: ws row 2048 -> uh[0],
    // still inside the workspace) and is unused.
    wp += DE;
    w0 = *(const float4*)(wp);
    w1 = *(const float4*)(wp + 4);
    float a[QT];
    #pragma unroll
    for (int q = 0; q < QT; ++q) {
      float A0 = fmaf(cw[0], eu[q][0], 1.f);
      float A1 = fmaf(cw[1], eu[q][1], 1.f);
      float A2 = fmaf(cw[2], eu[q][2], 1.f);
      float A3 = fmaf(cw[3], eu[q][3], 1.f);
      float B0 = fmaf(cw[4], eu[q][4], 1.f);
      float B1 = fmaf(cw[5], eu[q][5], 1.f);
      float B2 = fmaf(cw[6], eu[q][6], 1.f);
      float B3 = fmaf(cw[7], eu[q][7], 1.f);
      float n1 = fmaf(v[1], A0, v[0] * A1);
      float d1 = A0 * A1;
      float n2 = fmaf(v[3], A2, v[2] * A3);
      float d2 = A2 * A3;
      float N1 = fmaf(n2, d1, n1 * d2);
      float D1 = d1 * d2;
      float n3 = fmaf(v[5], B0, v[4] * B1);
      float d3 = B0 * B1;
      float n4 = fmaf(v[7], B2, v[6] * B3);
      float d4 = B2 * B3;
      float N2 = fmaf(n4, d3, n3 * d4);
      float D2 = d3 * d4;
      float s = N1 * __builtin_amdgcn_rcpf(D1);
      a[q] = fmaf(N2, __builtin_amdgcn_rcpf(D2), s);
    }
    // value-halving butterfly: 4 partials over 64 lanes -> lane l<4 holds q=l
    {
      const bool h1 = lane & 1;
      float m0 = h1 ? a[1] : a[0], o0 = h1 ? a[0] : a[1];
      float m1 = h1 ? a[3] : a[2], o1 = h1 ? a[2] : a[3];
      float r0 = m0 + __shfl_xor(o0, 1, 64);
      float r1 = m1 + __shfl_xor(o1, 1, 64);
      const bool h2 = lane & 2;
      float mm = h2 ? r1 : r0, oo = h2 ? r0 : r1;
      float r = mm + __shfl_xor(oo, 2, 64);
      r += __shfl_xor(r, 4, 64);
      r += __shfl_xor(r, 8, 64);
      r += __shfl_xor(r, 16, 64);
      r += __shfl_xor(r, 32, 64);
      if (lane < QT)
        out_s[(size_t)(b * TD + q0 + lane) * TE + t] = -2.f * r;
    }
  }
}

// ---- attn2: softmax + context (back half of the old attn, scores from global) --
// grid = 8b x 64qt = 512 blocks x 512 thr; b = blk&7 XCD swizzle.
__global__ __launch_bounds__(512) void attn2(
    const float* __restrict__ gs, const float* __restrict__ enc,
    float* __restrict__ out_c, float* __restrict__ out_e)
{
  const int tid  = threadIdx.x;
  const int wave = tid >> 6;
  const int lane = tid & 63;
  const int b  = blockIdx.x & 7;
  const int q0 = (blockIdx.x >> 3) * QT;
  __shared__ float s_sc[QT][TE];           // 4 KB
  __shared__ float red[3][QT][DE];         // 24 KB, context partials

  // ---- softmax: waves 0..3 handle row = wave ----
  if (wave < QT) {
    const int r = wave;
    const float* row = gs + (size_t)(b * TD + q0 + r) * TE;
    float x[4];
    #pragma unroll
    for (int i = 0; i < 4; ++i) x[i] = row[lane + 64 * i];
    float m = fmaxf(fmaxf(x[0], x[1]), fmaxf(x[2], x[3]));
    #pragma unroll
    for (int off = 32; off >= 1; off >>= 1) m = fmaxf(m, __shfl_xor(m, off, 64));
    const float L2E = 1.4426950408889634f;
    float ssum = 0.f;
    #pragma unroll
    for (int i = 0; i < 4; ++i) { x[i] = __builtin_amdgcn_exp2f((x[i] - m) * L2E); ssum += x[i]; }
    #pragma unroll
    for (int off = 32; off >= 1; off >>= 1) ssum += __shfl_xor(ssum, off, 64);
    float inv = 1.f / ssum;
    float* oe = out_e + (size_t)(b * TD + q0 + r) * TE;
    #pragma unroll
    for (int i = 0; i < 4; ++i) {
      float e = x[i] * inv;
      s_sc[r][lane + 64 * i] = e;
      oe[lane + 64 * i] = e;
    }
  }
  __syncthreads();

  // ---- context: c[q][f4..f4+3] = sum_t e[q][t]*enc[b][t][f4..f4+3] ----
  {
    const int fgrp = tid >> 7;           // 0..3
    const int f4   = (tid & 127) * 4;
    float4 c[QT];
    #pragma unroll
    for (int q = 0; q < QT; ++q) c[q] = make_float4(0.f, 0.f, 0.f, 0.f);
    const float* eb = enc + (size_t)b * TE * DE + f4;
    const int tb = fgrp * 64;
    #pragma unroll 4
    for (int t = tb; t < tb + 64; ++t) {
      float4 ee = *(const float4*)(eb + (size_t)t * DE);
      #pragma unroll
      for (int q = 0; q < QT; ++q) {
        float w = s_sc[q][t];
        c[q].x = fmaf(w, ee.x, c[q].x);
        c[q].y = fmaf(w, ee.y, c[q].y);
        c[q].z = fmaf(w, ee.z, c[q].z);
        c[q].w = fmaf(w, ee.w, c[q].w);
      }
    }
    if (fgrp > 0) {
      #pragma unroll
      for (int q = 0; q < QT; ++q) *(float4*)&red[fgrp - 1][q][f4] = c[q];
    }
    __syncthreads();
    if (fgrp == 0) {
      #pragma unroll
      for (int q = 0; q < QT; ++q) {
        float4 r1 = *(const float4*)&red[0][q][f4];
        float4 r2 = *(const float4*)&red[1][q][f4];
        float4 r3 = *(const float4*)&red[2][q][f4];
        c[q].x += (r1.x + r2.x) + r3.x;
        c[q].y += (r1.y + r2.y) + r3.y;
        c[q].z += (r1.z + r2.z) + r3.z;
        c[q].w += (r1.w + r2.w) + r3.w;
        *(float4*)(out_c + (size_t)(b * TD + q0 + q) * DE + f4) = c[q];
      }
    }
  }
}

extern "C" void kernel_launch(void* const* d_in, const int* in_sizes, int n_in,
                              void* d_out, int out_size, void* d_ws, size_t ws_size,
                              hipStream_t stream) {
  const float* enc = (const float*)d_in[0];
  const float* dec = (const float*)d_in[1];
  const float* Wa  = (const float*)d_in[2];
  const float* Ua  = (const float*)d_in[3];
  const float* Va  = (const float*)d_in[4];
  float* out_c = (float*)d_out;
  float* out_e = out_c + (size_t)NB * TD * DE;          // c first, then e

  // workspace layout (12 MB):
  float* ws = (float*)d_ws;                             // ew = e^{2Ws}: 4 MB
  float* uh = ws + 1048576;                             // eu = e^{2Uh}: 4 MB
  unsigned short* BHw = (unsigned short*)(uh + 1048576);// 0.5 MB each
  unsigned short* BLw = BHw + 262144;
  unsigned short* BHu = BLw + 262144;
  unsigned short* BLu = BHu + 262144;
  float* gsc = (float*)(BLu + 262144);                  // scores: 2 MB

  convB<<<dim3(16, 16, 2), dim3(256), 0, stream>>>(Wa, BHw, BLw, Ua, BHu, BLu);
  gemm_mfma<<<dim3(512), dim3(256), 0, stream>>>(
      enc, BHw, BLw, ws, dec, BHu, BLu, uh);
  scores<<<dim3(NB * (TD / QT) * 4), dim3(256), 0, stream>>>(ws, uh, Va, gsc);
  attn2<<<dim3(NB * (TD / QT)), dim3(512), 0, stream>>>(gsc, enc, out_c, out_e);
}